// Round 14
// baseline (294.602 us; speedup 1.0000x reference)
//
#include <hip/hip_runtime.h>

typedef _Float16 f16;
typedef __attribute__((__ext_vector_type__(2))) _Float16 f16x2;
typedef __attribute__((__ext_vector_type__(4))) _Float16 f16x4;
typedef __attribute__((__ext_vector_type__(8))) _Float16 f16x8;
typedef __attribute__((__ext_vector_type__(4))) float f32x4;

#define GLDS16(g, l) __builtin_amdgcn_global_load_lds( \
    (const __attribute__((address_space(1))) void*)(g), \
    (__attribute__((address_space(3))) void*)(l), 16, 0, 0)

// ---------------- constants ----------------
// x: (16,256,56,56)  w1: (128,256,7,7) dil=2 pad=6 -> k:(16,128,56,56)
// w2: (49,128) -> attn (16,49,56,56); out = sum_ij tap(x) * attn
// padded spatial 68x68 (orig (h,w) at padded (h+6,w+6); tap (i,j) of output
// (h,w) reads padded array index (h+2i, w+2j)).

// zero only the 12.2MB border of xpad (interior fully overwritten next).
__global__ __launch_bounds__(256) void zero_border(uint4* __restrict__ xp) {
  const int i = blockIdx.x * 256 + threadIdx.x;  // 0..761855
  int idx4;
  if (i < 417792) {  // full rows: 16b x 12r x 2176 u4
    int u = i % 2176;
    int row12 = i / 2176;
    int b = row12 / 12, r12 = row12 % 12;
    int r = (r12 < 6) ? r12 : r12 + 56;
    idx4 = (b * 68 + r) * 2176 + u;
  } else {  // side runs: 16b x 56r x 2 sides x 192 u4
    int j = i - 417792;
    int u = j % 192;
    int run = j / 192;
    int side = run & 1;
    int br = run >> 1;
    int r = br % 56 + 6, b = br / 56;
    idx4 = (b * 68 + r) * 2176 + (side ? 62 * 32 : 0) + u;
  }
  xp[idx4] = make_uint4(0u, 0u, 0u, 0u);
}

// x NCHW fp32 -> xpad NHWC fp16 (interior only). f16 LDS tile; b128-clean.
__global__ __launch_bounds__(256) void transpose_cast(
    const float* __restrict__ x, f16* __restrict__ xpad) {
  __shared__ f16 t16[56][258];
  const int bh = blockIdx.x;  // b*56 + h
  const int h = bh % 56, b = bh / 56;
  const float* xp = x + (size_t)b * 256 * 3136 + h * 56;
  for (int f = threadIdx.x; f < 256 * 56; f += 256) {
    int c = f / 56, w = f % 56;
    t16[w][c] = (f16)xp[(size_t)c * 3136 + w];
  }
  __syncthreads();
  f16* op = xpad + (((size_t)(b * 68) + h + 6) * 68 + 6) * 256;
  for (int g = threadIdx.x; g < 56 * 32; g += 256) {
    int w = g >> 5, c0 = (g & 31) * 8;
    *(f16x8*)(op + (size_t)w * 256 + c0) = *(const f16x8*)&t16[w][c0];
  }
}

// w1 (co,c,i,j) fp32 -> per-wave-fragment lane order (thread per (co,c):
// sequential 196B reads). Runs LAST so w1h is L2-hot for conv1.
// elem = (((ij*8 + cc8)*8 + f)*64 + q*16 + l15)*8 + e
//   co = f*16 + l15;  c = cc8*32 + q*8 + e   (cc8 = c>>5, 0..7)
__global__ __launch_bounds__(256) void w1_transform(
    const float* __restrict__ w1, f16* __restrict__ w1h) {
  const int idx = blockIdx.x * 256 + threadIdx.x;  // 0..32767
  const int co = idx >> 8, c = idx & 255;
  const int cc8 = c >> 5, q = (c >> 3) & 3, e = c & 7;
  const int f = co >> 4, l15 = co & 15;
  const size_t base = ((((size_t)cc8 * 8 + f) * 64 + q * 16 + l15) * 8 + e);
  const float* src = w1 + ((size_t)co * 256 + c) * 49;
#pragma unroll 7
  for (int ij = 0; ij < 49; ++ij)
    w1h[base + (size_t)ij * 32768] = (f16)src[ij];
}

// ---------------- conv1: merged-K 4-row-strip implicit GEMM -------------
// Block = (b, 4-row strip), ALL 256 channels (8 cc slices). Grid 224 ->
// exactly 1 block/CU. M=224 (14 m-frags), N=128; 4 waves own 7m x 4n.
// DOUBLE-BUFFERED strip (2 x 69.6KB = 139KB LDS): next cc slice's
// global_load_lds issues at tap-loop start and drains across 49 taps ->
// zero exposed stage time, 1 barrier per cc. A: tap-level register
// double-buffer (r13's win). B: 1-tap-ahead register prefetch; B-L2
// traffic per MFMA HALVED vs r13 (1 block/CU instead of 2).
__global__ __launch_bounds__(256, 1) void conv1_gemm(
    const f16* __restrict__ xpad, const f16* __restrict__ w1h,
    f16* __restrict__ kbuf) {
  __shared__ f16 strip0[16 * 68 * 32];  // 69632 B
  __shared__ f16 strip1[16 * 68 * 32];  // 69632 B

  const int tid = threadIdx.x;
  const int wid = tid >> 6, lane = tid & 63;
  // XCD-chunked bijective swizzle (224 % 8 == 0)
  const int pphys = blockIdx.x;
  const int sid = (pphys & 7) * 28 + (pphys >> 3);  // 0..223
  const int b = sid / 14;
  const int h0 = (sid % 14) * 4;

  const int l15 = lane & 15;
  const int q = lane >> 4;        // ch-quarter (16B) index
  const int qb = (l15 >> 1) & 3;  // (w>>1)&3, m-independent

  const int mbase = (wid >> 1) * 7;
  const int nbase = (wid & 1) * 4;

  int arow_off[7];
#pragma unroll
  for (int mm = 0; mm < 7; ++mm) {
    int p = (mbase + mm) * 16 + l15;
    int rw = p / 56;
    int w = p - 56 * rw;
    arow_off[mm] = (rw * 68 + w) * 64;
  }

  const char* xg = (const char*)xpad + ((size_t)(b * 68 + h0)) * (68 * 512);
  const char* wB = (const char*)w1h;
  char* Ss0 = (char*)strip0;
  char* Ss1 = (char*)strip1;

  auto loadB = [&](int cc8, int ij, int nn) -> f16x8 {
    int off = (((ij * 8 + cc8) * 8 + nbase + nn) * 64 + lane) * 16;
    return *(const f16x8*)(wB + off);
  };
  auto baseOff = [&](int ij) -> int {
    const int i = (int)((unsigned)ij / 7u);
    const int j = ij - 7 * i;
    return i * 8704 + j * 128 + ((q ^ ((qb + j) & 3)) << 4);
  };
  auto stage = [&](char* dst, int cc8) {
    const int chb = cc8 * 64;
#pragma unroll
    for (int rr = 0; rr < 17; ++rr) {
      int s = rr * 256 + tid;  // 16B-slot: s = r*272 + col*4 + q4
      int r = (int)((unsigned)s / 272u);
      int rem = s - r * 272;
      int col = rem >> 2, q4 = rem & 3;
      int qq = q4 ^ ((col >> 1) & 3);  // pre-swizzled source quarter
      GLDS16(xg + (size_t)r * (68 * 512) + col * 512 + chb + qq * 16,
             dst + (rr * 256 + wid * 64) * 16);
    }
  };

  f32x4 acc[7][4] = {};
  f16x8 pb0 = loadB(0, 0, 0), pb1 = loadB(0, 0, 1);
  f16x8 pb2 = loadB(0, 0, 2), pb3 = loadB(0, 0, 3);
  f16x8 A0[7], A1[7];

  stage(Ss0, 0);
  __syncthreads();  // vmcnt drained -> strip0 ready

  for (int cc8 = 0; cc8 < 8; ++cc8) {
    char* Sc = (cc8 & 1) ? Ss1 : Ss0;
    char* Sn = (cc8 & 1) ? Ss0 : Ss1;
    if (cc8 < 7) stage(Sn, cc8 + 1);  // async; drains across the 49 taps

    // prologue: A0 <- tap 0 of this slice
    {
      const int bo = baseOff(0);
#pragma unroll
      for (int mm = 0; mm < 7; ++mm)
        A0[mm] = *(const f16x8*)(Sc + arow_off[mm] + bo);
    }

    auto tapStep = [&](f16x8* Acur, f16x8* Anxt, int ij, bool loadA) {
      f16x8 b0 = pb0, b1 = pb1, b2 = pb2, b3 = pb3;
      int nij = ij + 1, ncc = cc8;
      if (nij == 49) { nij = 0; ++ncc; }
      if (ncc < 8) {
        pb0 = loadB(ncc, nij, 0);
        pb1 = loadB(ncc, nij, 1);
        pb2 = loadB(ncc, nij, 2);
        pb3 = loadB(ncc, nij, 3);
      }
      if (loadA) {
        const int bo = baseOff(ij + 1);
#pragma unroll
        for (int mm = 0; mm < 7; ++mm)
          Anxt[mm] = *(const f16x8*)(Sc + arow_off[mm] + bo);
      }
#pragma unroll
      for (int mm = 0; mm < 7; ++mm) {
        acc[mm][0] = __builtin_amdgcn_mfma_f32_16x16x32_f16(Acur[mm], b0,
                                                            acc[mm][0], 0, 0, 0);
        acc[mm][1] = __builtin_amdgcn_mfma_f32_16x16x32_f16(Acur[mm], b1,
                                                            acc[mm][1], 0, 0, 0);
        acc[mm][2] = __builtin_amdgcn_mfma_f32_16x16x32_f16(Acur[mm], b2,
                                                            acc[mm][2], 0, 0, 0);
        acc[mm][3] = __builtin_amdgcn_mfma_f32_16x16x32_f16(Acur[mm], b3,
                                                            acc[mm][3], 0, 0, 0);
      }
    };

    for (int pt = 0; pt < 24; ++pt) {
      tapStep(A0, A1, 2 * pt, true);      // consume A0, fill A1
      tapStep(A1, A0, 2 * pt + 1, true);  // consume A1, fill A0
    }
    tapStep(A0, A1, 48, false);  // tail tap, no A prefetch

    __syncthreads();  // stage loads drained; all waves done with Sc
  }

  // write fp16 result (full 256-ch sum): kbuf[p][co]
  const int pbase = (b * 56 + h0) * 56;
#pragma unroll
  for (int mm = 0; mm < 7; ++mm) {
#pragma unroll
    for (int nn = 0; nn < 4; ++nn) {
      const int co = (nbase + nn) * 16 + l15;
#pragma unroll
      for (int r = 0; r < 4; ++r) {
        int p = (mbase + mm) * 16 + q * 4 + r;
        int rw = p / 56;
        int w = p - 56 * rw;
        kbuf[(size_t)(pbase + rw * 56 + w) * 128 + co] = (f16)acc[mm][nn][r];
      }
    }
  }
}

// ---------------- bias + relu + 1x1 + BN + softmax ----------------------
__global__ __launch_bounds__(128) void conv2_bn_softmax(
    const f16* __restrict__ kbuf, const float* __restrict__ b1,
    const float* __restrict__ w2, const float* __restrict__ b2,
    const float* __restrict__ gamma, const float* __restrict__ beta,
    const float* __restrict__ rmean, const float* __restrict__ rvar,
    float* __restrict__ attn) {
  __shared__ f16 w2s[49 * 128];
  __shared__ float b1s[128];
  __shared__ float outs[128 * 49];
  for (int i = threadIdx.x; i < 49 * 128; i += 128) w2s[i] = (f16)w2[i];
  if (threadIdx.x < 128) b1s[threadIdx.x] = b1[threadIdx.x];
  __syncthreads();
  const int p = blockIdx.x * 128 + threadIdx.x;
  float acc[49];
#pragma unroll
  for (int o = 0; o < 49; ++o) acc[o] = 0.f;
  const f16x8* ka = (const f16x8*)(kbuf + (size_t)p * 128);
  for (int u = 0; u < 16; ++u) {
    f16x8 va = ka[u];
    f16x2 kvh[4];
#pragma unroll
    for (int j = 0; j < 4; ++j) {
      float s0 = (float)va[2 * j] + b1s[u * 8 + 2 * j];
      float s1 = (float)va[2 * j + 1] + b1s[u * 8 + 2 * j + 1];
      s0 = s0 > 0.f ? s0 : 0.f;
      s1 = s1 > 0.f ? s1 : 0.f;
      kvh[j] = f16x2{(f16)s0, (f16)s1};
    }
#pragma unroll
    for (int o = 0; o < 49; ++o) {
      f16x8 wv = *(const f16x8*)(w2s + o * 128 + u * 8);
#if __has_builtin(__builtin_amdgcn_fdot2)
      acc[o] = __builtin_amdgcn_fdot2(kvh[0], f16x2{wv[0], wv[1]}, acc[o], false);
      acc[o] = __builtin_amdgcn_fdot2(kvh[1], f16x2{wv[2], wv[3]}, acc[o], false);
      acc[o] = __builtin_amdgcn_fdot2(kvh[2], f16x2{wv[4], wv[5]}, acc[o], false);
      acc[o] = __builtin_amdgcn_fdot2(kvh[3], f16x2{wv[6], wv[7]}, acc[o], false);
#else
#pragma unroll
      for (int j = 0; j < 4; ++j)
        acc[o] += (float)kvh[j][0] * (float)wv[2 * j] +
                  (float)kvh[j][1] * (float)wv[2 * j + 1];
#endif
    }
  }
  float mx = -1e30f;
#pragma unroll
  for (int o = 0; o < 49; ++o) {
    float s = acc[o] + b2[o];
    float inv = gamma[o] * rsqrtf(rvar[o] + 1e-5f);
    s = (s - rmean[o]) * inv + beta[o];
    s = s > 0.f ? s : 0.f;
    acc[o] = s;
    mx = fmaxf(mx, s);
  }
  float sum = 0.f;
#pragma unroll
  for (int o = 0; o < 49; ++o) {
    float e = __expf(acc[o] - mx);
    acc[o] = e;
    sum += e;
  }
  const float rinv = 1.f / sum;
  float* orow = outs + threadIdx.x * 49;
#pragma unroll
  for (int o = 0; o < 49; ++o) orow[o] = acc[o] * rinv;
  __syncthreads();
  float* ab = attn + (size_t)blockIdx.x * (128 * 49);
  for (int i = threadIdx.x; i < 128 * 49; i += 128) ab[i] = outs[i];
}

// ---------------- attention-weighted aggregation (r8 scalar form) -------
__global__ __launch_bounds__(896, 1) void aggregate2(
    const f16* __restrict__ xpad, const float* __restrict__ attn,
    float* __restrict__ out) {
  __shared__ float t[256][57];  // 58368 B
  const int pp = blockIdx.x;
  const int bh = (pp & 7) * 112 + (pp >> 3);  // bijective: 896 = 8*112
  const int h = bh % 56, b = bh / 56;
  const int tid = threadIdx.x;
  const int wid = tid >> 6, lane = tid & 63;
  const int q = (wid < 7) ? wid * 8 : (wid - 7) * 8 + 1;

  int ap[4];
#pragma unroll
  for (int p = 0; p < 4; ++p) ap[p] = ((b * 56 + h) * 56 + q + 2 * p) * 49;

  float acc[4][4] = {};
  const f16* rowb = xpad + ((size_t)(b * 68 + h) * 68 + q) * 256 + 4 * lane;

  for (int i = 0; i < 7; ++i) {
    const f16* rb = rowb + (size_t)(2 * i * 68) * 256;
#pragma unroll
    for (int tt = 0; tt < 10; ++tt) {
      f16x4 xv = *(const f16x4*)(rb + tt * 512);  // 2 cols per tt step
      float xf[4];
#pragma unroll
      for (int k = 0; k < 4; ++k) xf[k] = (float)xv[k];
#pragma unroll
      for (int p = 0; p < 4; ++p) {
        const int j = tt - p;
        if (j >= 0 && j < 7) {
          const float a = attn[ap[p] + i * 7 + j];
#pragma unroll
          for (int k = 0; k < 4; ++k) acc[p][k] = fmaf(a, xf[k], acc[p][k]);
        }
      }
    }
  }

#pragma unroll
  for (int p = 0; p < 4; ++p)
#pragma unroll
    for (int k = 0; k < 4; ++k) t[4 * lane + k][q + 2 * p] = acc[p][k];
  __syncthreads();
  float* ob = out + ((size_t)b * 256 * 56 + h) * 56;
  for (int f = tid; f < 256 * 56; f += 896) {
    int c = f / 56, w = f % 56;
    ob[(size_t)c * 3136 + w] = t[c][w];
  }
}

// ---------------- launch ----------------
extern "C" void kernel_launch(void* const* d_in, const int* in_sizes, int n_in,
                              void* d_out, int out_size, void* d_ws,
                              size_t ws_size, hipStream_t stream) {
  const float* x = (const float*)d_in[0];
  const float* w1 = (const float*)d_in[1];
  const float* b1 = (const float*)d_in[2];
  const float* w2 = (const float*)d_in[3];
  const float* b2 = (const float*)d_in[4];
  const float* gamma = (const float*)d_in[5];
  const float* beta = (const float*)d_in[6];
  const float* rmean = (const float*)d_in[7];
  const float* rvar = (const float*)d_in[8];
  float* out = (float*)d_out;

  char* ws = (char*)d_ws;
  f16* xpad = (f16*)ws;                     // 16*68*68*256*2 = 37,879,808 B
  f16* w1h = (f16*)(ws + 37879808);         // 49*128*256*2  =  3,211,264 B
  f16* kbuf = (f16*)(ws + 41091072);        // 50176*128*2   = 12,845,056 B
  float* attn = (float*)(ws + 53936128);    // 50176*49*4    =  9,834,496 B

  hipLaunchKernelGGL(zero_border, dim3(2976), dim3(256), 0, stream,
                     (uint4*)xpad);
  hipLaunchKernelGGL(transpose_cast, dim3(896), dim3(256), 0, stream, x, xpad);
  hipLaunchKernelGGL(w1_transform, dim3(128), dim3(256), 0, stream, w1, w1h);
  hipLaunchKernelGGL(conv1_gemm, dim3(224), dim3(256), 0, stream, xpad, w1h,
                     kbuf);
  hipLaunchKernelGGL(conv2_bn_softmax, dim3(392), dim3(128), 0, stream, kbuf,
                     b1, w2, b2, gamma, beta, rmean, rvar, attn);
  hipLaunchKernelGGL(aggregate2, dim3(896), dim3(896), 0, stream, xpad, attn,
                     out);
}

// Round 15
// 244.480 us; speedup vs baseline: 1.2050x; 1.2050x over previous
//
#include <hip/hip_runtime.h>

typedef _Float16 f16;
typedef __attribute__((__ext_vector_type__(2))) _Float16 f16x2;
typedef __attribute__((__ext_vector_type__(4))) _Float16 f16x4;
typedef __attribute__((__ext_vector_type__(8))) _Float16 f16x8;
typedef __attribute__((__ext_vector_type__(4))) float f32x4;

#define GLDS16(g, l) __builtin_amdgcn_global_load_lds( \
    (const __attribute__((address_space(1))) void*)(g), \
    (__attribute__((address_space(3))) void*)(l), 16, 0, 0)

// ---------------- constants ----------------
// x: (16,256,56,56)  w1: (128,256,7,7) dil=2 pad=6 -> k:(16,128,56,56)
// w2: (49,128) -> attn (16,49,56,56); out = sum_ij tap(x) * attn
// padded spatial 68x68 (orig (h,w) at padded (h+6,w+6); tap (i,j) of output
// (h,w) reads padded array index (h+2i, w+2j)).

// ---- fused small prep: w1 layout (blocks 0..127) + zero border (rest) ---
// w1 (co,c,i,j) fp32 -> per-wave-fragment lane order (thread per (co,c)):
// elem = (((ij*8 + half*4 + cc)*8 + f)*64 + q*16 + l15)*8 + e
//   co = f*16 + l15;  c = half*128 + cc*32 + q*8 + e
__global__ __launch_bounds__(256) void prep_misc(
    const float* __restrict__ w1, f16* __restrict__ w1h,
    uint4* __restrict__ xp) {
  const int blk = blockIdx.x;
  const int tid = threadIdx.x;
  if (blk < 128) {
    const int idx = blk * 256 + tid;  // 0..32767
    const int co = idx >> 8, c = idx & 255;
    const int half = c >> 7, cc = (c >> 5) & 3, q = (c >> 3) & 3, e = c & 7;
    const int f = co >> 4, l15 = co & 15;
    const size_t base =
        ((((size_t)(half * 4 + cc) * 8 + f) * 64 + q * 16 + l15) * 8 + e);
    const float* src = w1 + ((size_t)co * 256 + c) * 49;
#pragma unroll 7
    for (int ij = 0; ij < 49; ++ij)
      w1h[base + (size_t)ij * 32768] = (f16)src[ij];
  } else {
    const int i = (blk - 128) * 256 + tid;  // 0..761855
    int idx4;
    if (i < 417792) {  // full rows: 16b x 12r x 2176 u4
      int u = i % 2176;
      int row12 = i / 2176;
      int b = row12 / 12, r12 = row12 % 12;
      int r = (r12 < 6) ? r12 : r12 + 56;
      idx4 = (b * 68 + r) * 2176 + u;
    } else {  // side runs: 16b x 56r x 2 sides x 192 u4
      int j = i - 417792;
      int u = j % 192;
      int run = j / 192;
      int side = run & 1;
      int br = run >> 1;
      int r = br % 56 + 6, b = br / 56;
      idx4 = (b * 68 + r) * 2176 + (side ? 62 * 32 : 0) + u;
    }
    xp[idx4] = make_uint4(0u, 0u, 0u, 0u);
  }
}

// x NCHW fp32 -> xpad NHWC fp16 (interior only). f16 LDS tile; b128-clean.
__global__ __launch_bounds__(256) void transpose_cast(
    const float* __restrict__ x, f16* __restrict__ xpad) {
  __shared__ f16 t16[56][258];
  const int bh = blockIdx.x;  // b*56 + h
  const int h = bh % 56, b = bh / 56;
  const float* xp = x + (size_t)b * 256 * 3136 + h * 56;
  for (int f = threadIdx.x; f < 256 * 56; f += 256) {
    int c = f / 56, w = f % 56;
    t16[w][c] = (f16)xp[(size_t)c * 3136 + w];
  }
  __syncthreads();
  f16* op = xpad + (((size_t)(b * 68) + h + 6) * 68 + 6) * 256;
  for (int g = threadIdx.x; g < 56 * 32; g += 256) {
    int w = g >> 5, c0 = (g & 31) * 8;
    *(f16x8*)(op + (size_t)w * 256 + c0) = *(const f16x8*)&t16[w][c0];
  }
}

// ---------------- conv1: 4-row-strip implicit GEMM, A double-buffer -----
// r13 form VERBATIM (best measured: 141us, MfmaUtil 51%). Block = (b,
// 4-row strip, channel-half), 2 blocks/CU (>=2 waves/SIMD is a hard
// constraint -- r14's 1-block/CU merged-K regressed to 204us). A:
// XOR-swizzled strip staged per cc slice; tap-level A register double-
// buffer hides the LDS pipe under MFMA (the r8-r11 additive-pipes fix).
// B: 1-tap-ahead register prefetch from w1h (per-XCD-L2-hot).
__global__ __launch_bounds__(256, 2) void conv1_gemm(
    const f16* __restrict__ xpad, const f16* __restrict__ w1h,
    f16* __restrict__ kbuf) {
  __shared__ f16 strip[16 * 68 * 32];  // 69632 B

  const int tid = threadIdx.x;
  const int wid = tid >> 6, lane = tid & 63;
  // XCD-chunked bijective swizzle (448 % 8 == 0)
  const int pphys = blockIdx.x;
  const int bid = (pphys & 7) * 56 + (pphys >> 3);
  const int half = bid & 1;
  const int sid = bid >> 1;  // 0..223
  const int b = sid / 14;
  const int h0 = (sid % 14) * 4;

  const int l15 = lane & 15;
  const int q = lane >> 4;        // ch-quarter (16B) index
  const int qb = (l15 >> 1) & 3;  // (w>>1)&3, m-independent

  const int mbase = (wid >> 1) * 7;
  const int nbase = (wid & 1) * 4;

  int arow_off[7];
#pragma unroll
  for (int mm = 0; mm < 7; ++mm) {
    int p = (mbase + mm) * 16 + l15;
    int rw = p / 56;
    int w = p - 56 * rw;
    arow_off[mm] = (rw * 68 + w) * 64;
  }

  const char* xg = (const char*)xpad +
                   ((size_t)(b * 68 + h0)) * (68 * 512) + half * 256;
  const char* wB = (const char*)w1h;
  char* Ss = (char*)strip;

  const int half4 = half * 4;
  auto loadB = [&](int cc, int ij, int nn) -> f16x8 {
    int off = (((ij * 8 + half4 + cc) * 8 + nbase + nn) * 64 + lane) * 16;
    return *(const f16x8*)(wB + off);
  };
  auto baseOff = [&](int ij) -> int {
    const int i = (int)((unsigned)ij / 7u);
    const int j = ij - 7 * i;
    return i * 8704 + j * 128 + ((q ^ ((qb + j) & 3)) << 4);
  };

  f32x4 acc[7][4] = {};
  f16x8 pb0 = loadB(0, 0, 0), pb1 = loadB(0, 0, 1);
  f16x8 pb2 = loadB(0, 0, 2), pb3 = loadB(0, 0, 3);
  f16x8 A0[7], A1[7];

  for (int cc = 0; cc < 4; ++cc) {
    const int chb = cc * 64;
    __syncthreads();  // prior cc's consumers done with strip
#pragma unroll
    for (int rr = 0; rr < 17; ++rr) {
      int s = rr * 256 + tid;  // 16B-slot: s = r*272 + col*4 + q4
      int r = (int)((unsigned)s / 272u);
      int rem = s - r * 272;
      int col = rem >> 2, q4 = rem & 3;
      int qq = q4 ^ ((col >> 1) & 3);  // pre-swizzled source quarter
      GLDS16(xg + (size_t)r * (68 * 512) + col * 512 + chb + qq * 16,
             Ss + (rr * 256 + wid * 64) * 16);
    }
    __syncthreads();  // strip ready

    // prologue: A0 <- tap 0 of this cc
    {
      const int bo = baseOff(0);
#pragma unroll
      for (int mm = 0; mm < 7; ++mm)
        A0[mm] = *(const f16x8*)(Ss + arow_off[mm] + bo);
    }

    auto tapStep = [&](f16x8* Acur, f16x8* Anxt, int ij, bool loadA) {
      f16x8 b0 = pb0, b1 = pb1, b2 = pb2, b3 = pb3;
      int nij = ij + 1, ncc = cc;
      if (nij == 49) { nij = 0; ++ncc; }
      if (ncc < 4) {
        pb0 = loadB(ncc, nij, 0);
        pb1 = loadB(ncc, nij, 1);
        pb2 = loadB(ncc, nij, 2);
        pb3 = loadB(ncc, nij, 3);
      }
      if (loadA) {
        const int bo = baseOff(ij + 1);
#pragma unroll
        for (int mm = 0; mm < 7; ++mm)
          Anxt[mm] = *(const f16x8*)(Ss + arow_off[mm] + bo);
      }
#pragma unroll
      for (int mm = 0; mm < 7; ++mm) {
        acc[mm][0] = __builtin_amdgcn_mfma_f32_16x16x32_f16(Acur[mm], b0,
                                                            acc[mm][0], 0, 0, 0);
        acc[mm][1] = __builtin_amdgcn_mfma_f32_16x16x32_f16(Acur[mm], b1,
                                                            acc[mm][1], 0, 0, 0);
        acc[mm][2] = __builtin_amdgcn_mfma_f32_16x16x32_f16(Acur[mm], b2,
                                                            acc[mm][2], 0, 0, 0);
        acc[mm][3] = __builtin_amdgcn_mfma_f32_16x16x32_f16(Acur[mm], b3,
                                                            acc[mm][3], 0, 0, 0);
      }
    };

    for (int pt = 0; pt < 24; ++pt) {
      tapStep(A0, A1, 2 * pt, true);      // consume A0, fill A1
      tapStep(A1, A0, 2 * pt + 1, true);  // consume A1, fill A0
    }
    tapStep(A0, A1, 48, false);  // tail tap, no A prefetch
  }

  // write fp16 partials: kh[p][co], p = (b*56 + h0 + rw)*56 + w
  f16* kh = kbuf + (size_t)half * (50176 * 128);
  const int pbase = (b * 56 + h0) * 56;
#pragma unroll
  for (int mm = 0; mm < 7; ++mm) {
#pragma unroll
    for (int nn = 0; nn < 4; ++nn) {
      const int co = (nbase + nn) * 16 + l15;
#pragma unroll
      for (int r = 0; r < 4; ++r) {
        int p = (mbase + mm) * 16 + q * 4 + r;
        int rw = p / 56;
        int w = p - 56 * rw;
        kh[(size_t)(pbase + rw * 56 + w) * 128 + co] = (f16)acc[mm][nn][r];
      }
    }
  }
}

// ---------------- sum halves + bias + relu + 1x1 + BN + softmax ---------
// 64 threads x 784 blocks: LDS 25.6KB -> 6 blocks/CU, 4x the TLP of the
// 128-thr config for the uniform-ds_read-latency-bound dot loop.
__global__ __launch_bounds__(64) void conv2_bn_softmax(
    const f16* __restrict__ kbuf, const float* __restrict__ b1,
    const float* __restrict__ w2, const float* __restrict__ b2,
    const float* __restrict__ gamma, const float* __restrict__ beta,
    const float* __restrict__ rmean, const float* __restrict__ rvar,
    float* __restrict__ attn) {
  __shared__ f16 w2s[49 * 128];
  __shared__ float b1s[128];
  __shared__ float outs[64 * 49];
  for (int i = threadIdx.x; i < 49 * 128; i += 64) w2s[i] = (f16)w2[i];
  for (int i = threadIdx.x; i < 128; i += 64) b1s[i] = b1[i];
  __syncthreads();
  const int p = blockIdx.x * 64 + threadIdx.x;
  float acc[49];
#pragma unroll
  for (int o = 0; o < 49; ++o) acc[o] = 0.f;
  const f16x8* ka = (const f16x8*)(kbuf + (size_t)p * 128);
  const f16x8* kb = (const f16x8*)(kbuf + (size_t)50176 * 128 + (size_t)p * 128);
  for (int u = 0; u < 16; ++u) {
    f16x8 va = ka[u], vb = kb[u];
    f16x2 kvh[4];
#pragma unroll
    for (int j = 0; j < 4; ++j) {
      float s0 = (float)va[2 * j] + (float)vb[2 * j] + b1s[u * 8 + 2 * j];
      float s1 =
          (float)va[2 * j + 1] + (float)vb[2 * j + 1] + b1s[u * 8 + 2 * j + 1];
      s0 = s0 > 0.f ? s0 : 0.f;
      s1 = s1 > 0.f ? s1 : 0.f;
      kvh[j] = f16x2{(f16)s0, (f16)s1};
    }
#pragma unroll
    for (int o = 0; o < 49; ++o) {
      f16x8 wv = *(const f16x8*)(w2s + o * 128 + u * 8);
#if __has_builtin(__builtin_amdgcn_fdot2)
      acc[o] = __builtin_amdgcn_fdot2(kvh[0], f16x2{wv[0], wv[1]}, acc[o], false);
      acc[o] = __builtin_amdgcn_fdot2(kvh[1], f16x2{wv[2], wv[3]}, acc[o], false);
      acc[o] = __builtin_amdgcn_fdot2(kvh[2], f16x2{wv[4], wv[5]}, acc[o], false);
      acc[o] = __builtin_amdgcn_fdot2(kvh[3], f16x2{wv[6], wv[7]}, acc[o], false);
#else
#pragma unroll
      for (int j = 0; j < 4; ++j)
        acc[o] += (float)kvh[j][0] * (float)wv[2 * j] +
                  (float)kvh[j][1] * (float)wv[2 * j + 1];
#endif
    }
  }
  float mx = -1e30f;
#pragma unroll
  for (int o = 0; o < 49; ++o) {
    float s = acc[o] + b2[o];
    float inv = gamma[o] * rsqrtf(rvar[o] + 1e-5f);
    s = (s - rmean[o]) * inv + beta[o];
    s = s > 0.f ? s : 0.f;
    acc[o] = s;
    mx = fmaxf(mx, s);
  }
  float sum = 0.f;
#pragma unroll
  for (int o = 0; o < 49; ++o) {
    float e = __expf(acc[o] - mx);
    acc[o] = e;
    sum += e;
  }
  const float rinv = 1.f / sum;
  float* orow = outs + threadIdx.x * 49;
#pragma unroll
  for (int o = 0; o < 49; ++o) orow[o] = acc[o] * rinv;
  __syncthreads();
  float* ab = attn + (size_t)blockIdx.x * (64 * 49);
  for (int i = threadIdx.x; i < 64 * 49; i += 64) ab[i] = outs[i];
}

// ---------------- attention-weighted aggregation (r8 scalar form) -------
__global__ __launch_bounds__(896, 1) void aggregate2(
    const f16* __restrict__ xpad, const float* __restrict__ attn,
    float* __restrict__ out) {
  __shared__ float t[256][57];  // 58368 B
  const int pp = blockIdx.x;
  const int bh = (pp & 7) * 112 + (pp >> 3);  // bijective: 896 = 8*112
  const int h = bh % 56, b = bh / 56;
  const int tid = threadIdx.x;
  const int wid = tid >> 6, lane = tid & 63;
  const int q = (wid < 7) ? wid * 8 : (wid - 7) * 8 + 1;

  int ap[4];
#pragma unroll
  for (int p = 0; p < 4; ++p) ap[p] = ((b * 56 + h) * 56 + q + 2 * p) * 49;

  float acc[4][4] = {};
  const f16* rowb = xpad + ((size_t)(b * 68 + h) * 68 + q) * 256 + 4 * lane;

  for (int i = 0; i < 7; ++i) {
    const f16* rb = rowb + (size_t)(2 * i * 68) * 256;
#pragma unroll
    for (int tt = 0; tt < 10; ++tt) {
      f16x4 xv = *(const f16x4*)(rb + tt * 512);  // 2 cols per tt step
      float xf[4];
#pragma unroll
      for (int k = 0; k < 4; ++k) xf[k] = (float)xv[k];
#pragma unroll
      for (int p = 0; p < 4; ++p) {
        const int j = tt - p;
        if (j >= 0 && j < 7) {
          const float a = attn[ap[p] + i * 7 + j];
#pragma unroll
          for (int k = 0; k < 4; ++k) acc[p][k] = fmaf(a, xf[k], acc[p][k]);
        }
      }
    }
  }

#pragma unroll
  for (int p = 0; p < 4; ++p)
#pragma unroll
    for (int k = 0; k < 4; ++k) t[4 * lane + k][q + 2 * p] = acc[p][k];
  __syncthreads();
  float* ob = out + ((size_t)b * 256 * 56 + h) * 56;
  for (int f = tid; f < 256 * 56; f += 896) {
    int c = f / 56, w = f % 56;
    ob[(size_t)c * 3136 + w] = t[c][w];
  }
}

// ---------------- launch ----------------
extern "C" void kernel_launch(void* const* d_in, const int* in_sizes, int n_in,
                              void* d_out, int out_size, void* d_ws,
                              size_t ws_size, hipStream_t stream) {
  const float* x = (const float*)d_in[0];
  const float* w1 = (const float*)d_in[1];
  const float* b1 = (const float*)d_in[2];
  const float* w2 = (const float*)d_in[3];
  const float* b2 = (const float*)d_in[4];
  const float* gamma = (const float*)d_in[5];
  const float* beta = (const float*)d_in[6];
  const float* rmean = (const float*)d_in[7];
  const float* rvar = (const float*)d_in[8];
  float* out = (float*)d_out;

  char* ws = (char*)d_ws;
  f16* xpad = (f16*)ws;                     // 16*68*68*256*2 = 37,879,808 B
  f16* w1h = (f16*)(ws + 37879808);         // 49*128*256*2  =  3,211,264 B
  f16* kbuf = (f16*)(ws + 41091072);        // 2*50176*128*2 = 25,690,112 B
  float* attn = (float*)(ws + 66781184);    // 50176*49*4    =  9,834,496 B

  hipLaunchKernelGGL(prep_misc, dim3(3104), dim3(256), 0, stream, w1, w1h,
                     (uint4*)xpad);
  hipLaunchKernelGGL(transpose_cast, dim3(896), dim3(256), 0, stream, x, xpad);
  hipLaunchKernelGGL(conv1_gemm, dim3(448), dim3(256), 0, stream, xpad, w1h,
                     kbuf);
  hipLaunchKernelGGL(conv2_bn_softmax, dim3(784), dim3(64), 0, stream, kbuf,
                     b1, w2, b2, gamma, beta, rmean, rvar, attn);
  hipLaunchKernelGGL(aggregate2, dim3(896), dim3(896), 0, stream, xpad, attn,
                     out);
}

// Round 16
// 244.408 us; speedup vs baseline: 1.2054x; 1.0003x over previous
//
#include <hip/hip_runtime.h>

typedef _Float16 f16;
typedef __attribute__((__ext_vector_type__(2))) _Float16 f16x2;
typedef __attribute__((__ext_vector_type__(4))) _Float16 f16x4;
typedef __attribute__((__ext_vector_type__(8))) _Float16 f16x8;
typedef __attribute__((__ext_vector_type__(4))) float f32x4;

#define GLDS16(g, l) __builtin_amdgcn_global_load_lds( \
    (const __attribute__((address_space(1))) void*)(g), \
    (__attribute__((address_space(3))) void*)(l), 16, 0, 0)

// ---------------- constants ----------------
// x: (16,256,56,56)  w1: (128,256,7,7) dil=2 pad=6 -> k:(16,128,56,56)
// w2: (49,128) -> attn (16,49,56,56); out = sum_ij tap(x) * attn
// padded spatial 68x68 (orig (h,w) at padded (h+6,w+6); tap (i,j) of output
// (h,w) reads padded array index (h+2i, w+2j)).

// ---- fused small prep: w1 layout (blocks 0..127) + zero border (rest) ---
__global__ __launch_bounds__(256) void prep_misc(
    const float* __restrict__ w1, f16* __restrict__ w1h,
    uint4* __restrict__ xp) {
  const int blk = blockIdx.x;
  const int tid = threadIdx.x;
  if (blk < 128) {
    const int idx = blk * 256 + tid;  // 0..32767
    const int co = idx >> 8, c = idx & 255;
    const int half = c >> 7, cc = (c >> 5) & 3, q = (c >> 3) & 3, e = c & 7;
    const int f = co >> 4, l15 = co & 15;
    const size_t base =
        ((((size_t)(half * 4 + cc) * 8 + f) * 64 + q * 16 + l15) * 8 + e);
    const float* src = w1 + ((size_t)co * 256 + c) * 49;
#pragma unroll 7
    for (int ij = 0; ij < 49; ++ij)
      w1h[base + (size_t)ij * 32768] = (f16)src[ij];
  } else {
    const int i = (blk - 128) * 256 + tid;  // 0..761855
    int idx4;
    if (i < 417792) {  // full rows: 16b x 12r x 2176 u4
      int u = i % 2176;
      int row12 = i / 2176;
      int b = row12 / 12, r12 = row12 % 12;
      int r = (r12 < 6) ? r12 : r12 + 56;
      idx4 = (b * 68 + r) * 2176 + u;
    } else {  // side runs: 16b x 56r x 2 sides x 192 u4
      int j = i - 417792;
      int u = j % 192;
      int run = j / 192;
      int side = run & 1;
      int br = run >> 1;
      int r = br % 56 + 6, b = br / 56;
      idx4 = (b * 68 + r) * 2176 + (side ? 62 * 32 : 0) + u;
    }
    xp[idx4] = make_uint4(0u, 0u, 0u, 0u);
  }
}

// x NCHW fp32 -> xpad NHWC fp16 (interior only). float4-vectorized reads
// (16B/lane; was scalar 4B/lane = 4x the VMEM issue). f16 LDS tile.
__global__ __launch_bounds__(256) void transpose_cast(
    const float* __restrict__ x, f16* __restrict__ xpad) {
  __shared__ f16 t16[56][258];
  const int bh = blockIdx.x;  // b*56 + h
  const int h = bh % 56, b = bh / 56;
  const float4* xp4 =
      (const float4*)(x + (size_t)b * 256 * 3136 + (size_t)h * 56);
  for (int f = threadIdx.x; f < 256 * 14; f += 256) {
    int c = f / 14, w4 = f % 14;
    float4 v = xp4[(size_t)c * 784 + w4];  // row stride 3136 f32 = 784 f4
    int w = w4 * 4;
    t16[w + 0][c] = (f16)v.x;
    t16[w + 1][c] = (f16)v.y;
    t16[w + 2][c] = (f16)v.z;
    t16[w + 3][c] = (f16)v.w;
  }
  __syncthreads();
  f16* op = xpad + (((size_t)(b * 68) + h + 6) * 68 + 6) * 256;
  for (int g = threadIdx.x; g < 56 * 32; g += 256) {
    int w = g >> 5, c0 = (g & 31) * 8;
    *(f16x8*)(op + (size_t)w * 256 + c0) = *(const f16x8*)&t16[w][c0];
  }
}

// ---------------- conv1: 4-row-strip implicit GEMM, A double-buffer -----
// FROZEN r13/r15 form (best measured: 141us, MfmaUtil 51%). Block = (b,
// 4-row strip, channel-half), 2 blocks/CU (>=2 waves/SIMD hard constraint
// -- r14's 1-block/CU merged-K regressed to 204us). A: XOR-swizzled strip
// staged per cc slice; tap-level A register double-buffer hides the LDS
// pipe under MFMA. B: 1-tap-ahead register prefetch from w1h (L2-hot).
__global__ __launch_bounds__(256, 2) void conv1_gemm(
    const f16* __restrict__ xpad, const f16* __restrict__ w1h,
    f16* __restrict__ kbuf) {
  __shared__ f16 strip[16 * 68 * 32];  // 69632 B

  const int tid = threadIdx.x;
  const int wid = tid >> 6, lane = tid & 63;
  // XCD-chunked bijective swizzle (448 % 8 == 0)
  const int pphys = blockIdx.x;
  const int bid = (pphys & 7) * 56 + (pphys >> 3);
  const int half = bid & 1;
  const int sid = bid >> 1;  // 0..223
  const int b = sid / 14;
  const int h0 = (sid % 14) * 4;

  const int l15 = lane & 15;
  const int q = lane >> 4;        // ch-quarter (16B) index
  const int qb = (l15 >> 1) & 3;  // (w>>1)&3, m-independent

  const int mbase = (wid >> 1) * 7;
  const int nbase = (wid & 1) * 4;

  int arow_off[7];
#pragma unroll
  for (int mm = 0; mm < 7; ++mm) {
    int p = (mbase + mm) * 16 + l15;
    int rw = p / 56;
    int w = p - 56 * rw;
    arow_off[mm] = (rw * 68 + w) * 64;
  }

  const char* xg = (const char*)xpad +
                   ((size_t)(b * 68 + h0)) * (68 * 512) + half * 256;
  const char* wB = (const char*)w1h;
  char* Ss = (char*)strip;

  const int half4 = half * 4;
  auto loadB = [&](int cc, int ij, int nn) -> f16x8 {
    int off = (((ij * 8 + half4 + cc) * 8 + nbase + nn) * 64 + lane) * 16;
    return *(const f16x8*)(wB + off);
  };
  auto baseOff = [&](int ij) -> int {
    const int i = (int)((unsigned)ij / 7u);
    const int j = ij - 7 * i;
    return i * 8704 + j * 128 + ((q ^ ((qb + j) & 3)) << 4);
  };

  f32x4 acc[7][4] = {};
  f16x8 pb0 = loadB(0, 0, 0), pb1 = loadB(0, 0, 1);
  f16x8 pb2 = loadB(0, 0, 2), pb3 = loadB(0, 0, 3);
  f16x8 A0[7], A1[7];

  for (int cc = 0; cc < 4; ++cc) {
    const int chb = cc * 64;
    __syncthreads();  // prior cc's consumers done with strip
#pragma unroll
    for (int rr = 0; rr < 17; ++rr) {
      int s = rr * 256 + tid;  // 16B-slot: s = r*272 + col*4 + q4
      int r = (int)((unsigned)s / 272u);
      int rem = s - r * 272;
      int col = rem >> 2, q4 = rem & 3;
      int qq = q4 ^ ((col >> 1) & 3);  // pre-swizzled source quarter
      GLDS16(xg + (size_t)r * (68 * 512) + col * 512 + chb + qq * 16,
             Ss + (rr * 256 + wid * 64) * 16);
    }
    __syncthreads();  // strip ready

    // prologue: A0 <- tap 0 of this cc
    {
      const int bo = baseOff(0);
#pragma unroll
      for (int mm = 0; mm < 7; ++mm)
        A0[mm] = *(const f16x8*)(Ss + arow_off[mm] + bo);
    }

    auto tapStep = [&](f16x8* Acur, f16x8* Anxt, int ij, bool loadA) {
      f16x8 b0 = pb0, b1 = pb1, b2 = pb2, b3 = pb3;
      int nij = ij + 1, ncc = cc;
      if (nij == 49) { nij = 0; ++ncc; }
      if (ncc < 4) {
        pb0 = loadB(ncc, nij, 0);
        pb1 = loadB(ncc, nij, 1);
        pb2 = loadB(ncc, nij, 2);
        pb3 = loadB(ncc, nij, 3);
      }
      if (loadA) {
        const int bo = baseOff(ij + 1);
#pragma unroll
        for (int mm = 0; mm < 7; ++mm)
          Anxt[mm] = *(const f16x8*)(Ss + arow_off[mm] + bo);
      }
#pragma unroll
      for (int mm = 0; mm < 7; ++mm) {
        acc[mm][0] = __builtin_amdgcn_mfma_f32_16x16x32_f16(Acur[mm], b0,
                                                            acc[mm][0], 0, 0, 0);
        acc[mm][1] = __builtin_amdgcn_mfma_f32_16x16x32_f16(Acur[mm], b1,
                                                            acc[mm][1], 0, 0, 0);
        acc[mm][2] = __builtin_amdgcn_mfma_f32_16x16x32_f16(Acur[mm], b2,
                                                            acc[mm][2], 0, 0, 0);
        acc[mm][3] = __builtin_amdgcn_mfma_f32_16x16x32_f16(Acur[mm], b3,
                                                            acc[mm][3], 0, 0, 0);
      }
    };

    for (int pt = 0; pt < 24; ++pt) {
      tapStep(A0, A1, 2 * pt, true);      // consume A0, fill A1
      tapStep(A1, A0, 2 * pt + 1, true);  // consume A1, fill A0
    }
    tapStep(A0, A1, 48, false);  // tail tap, no A prefetch
  }

  // write fp16 partials: kh[p][co], p = (b*56 + h0 + rw)*56 + w
  f16* kh = kbuf + (size_t)half * (50176 * 128);
  const int pbase = (b * 56 + h0) * 56;
#pragma unroll
  for (int mm = 0; mm < 7; ++mm) {
#pragma unroll
    for (int nn = 0; nn < 4; ++nn) {
      const int co = (nbase + nn) * 16 + l15;
#pragma unroll
      for (int r = 0; r < 4; ++r) {
        int p = (mbase + mm) * 16 + q * 4 + r;
        int rw = p / 56;
        int w = p - 56 * rw;
        kh[(size_t)(pbase + rw * 56 + w) * 128 + co] = (f16)acc[mm][nn][r];
      }
    }
  }
}

// ---------------- sum halves + bias + relu + 1x1 + BN + softmax ---------
__global__ __launch_bounds__(64) void conv2_bn_softmax(
    const f16* __restrict__ kbuf, const float* __restrict__ b1,
    const float* __restrict__ w2, const float* __restrict__ b2,
    const float* __restrict__ gamma, const float* __restrict__ beta,
    const float* __restrict__ rmean, const float* __restrict__ rvar,
    float* __restrict__ attn) {
  __shared__ f16 w2s[49 * 128];
  __shared__ float b1s[128];
  __shared__ float outs[64 * 49];
  for (int i = threadIdx.x; i < 49 * 128; i += 64) w2s[i] = (f16)w2[i];
  for (int i = threadIdx.x; i < 128; i += 64) b1s[i] = b1[i];
  __syncthreads();
  const int p = blockIdx.x * 64 + threadIdx.x;
  float acc[49];
#pragma unroll
  for (int o = 0; o < 49; ++o) acc[o] = 0.f;
  const f16x8* ka = (const f16x8*)(kbuf + (size_t)p * 128);
  const f16x8* kb = (const f16x8*)(kbuf + (size_t)50176 * 128 + (size_t)p * 128);
  for (int u = 0; u < 16; ++u) {
    f16x8 va = ka[u], vb = kb[u];
    f16x2 kvh[4];
#pragma unroll
    for (int j = 0; j < 4; ++j) {
      float s0 = (float)va[2 * j] + (float)vb[2 * j] + b1s[u * 8 + 2 * j];
      float s1 =
          (float)va[2 * j + 1] + (float)vb[2 * j + 1] + b1s[u * 8 + 2 * j + 1];
      s0 = s0 > 0.f ? s0 : 0.f;
      s1 = s1 > 0.f ? s1 : 0.f;
      kvh[j] = f16x2{(f16)s0, (f16)s1};
    }
#pragma unroll
    for (int o = 0; o < 49; ++o) {
      f16x8 wv = *(const f16x8*)(w2s + o * 128 + u * 8);
#if __has_builtin(__builtin_amdgcn_fdot2)
      acc[o] = __builtin_amdgcn_fdot2(kvh[0], f16x2{wv[0], wv[1]}, acc[o], false);
      acc[o] = __builtin_amdgcn_fdot2(kvh[1], f16x2{wv[2], wv[3]}, acc[o], false);
      acc[o] = __builtin_amdgcn_fdot2(kvh[2], f16x2{wv[4], wv[5]}, acc[o], false);
      acc[o] = __builtin_amdgcn_fdot2(kvh[3], f16x2{wv[6], wv[7]}, acc[o], false);
#else
#pragma unroll
      for (int j = 0; j < 4; ++j)
        acc[o] += (float)kvh[j][0] * (float)wv[2 * j] +
                  (float)kvh[j][1] * (float)wv[2 * j + 1];
#endif
    }
  }
  float mx = -1e30f;
#pragma unroll
  for (int o = 0; o < 49; ++o) {
    float s = acc[o] + b2[o];
    float inv = gamma[o] * rsqrtf(rvar[o] + 1e-5f);
    s = (s - rmean[o]) * inv + beta[o];
    s = s > 0.f ? s : 0.f;
    acc[o] = s;
    mx = fmaxf(mx, s);
  }
  float sum = 0.f;
#pragma unroll
  for (int o = 0; o < 49; ++o) {
    float e = __expf(acc[o] - mx);
    acc[o] = e;
    sum += e;
  }
  const float rinv = 1.f / sum;
  float* orow = outs + threadIdx.x * 49;
#pragma unroll
  for (int o = 0; o < 49; ++o) orow[o] = acc[o] * rinv;
  __syncthreads();
  float* ab = attn + (size_t)blockIdx.x * (64 * 49);
  for (int i = threadIdx.x; i < 64 * 49; i += 64) ab[i] = outs[i];
}

// ---------------- attention-weighted aggregation (r8 scalar form) -------
__global__ __launch_bounds__(896, 1) void aggregate2(
    const f16* __restrict__ xpad, const float* __restrict__ attn,
    float* __restrict__ out) {
  __shared__ float t[256][57];  // 58368 B
  const int pp = blockIdx.x;
  const int bh = (pp & 7) * 112 + (pp >> 3);  // bijective: 896 = 8*112
  const int h = bh % 56, b = bh / 56;
  const int tid = threadIdx.x;
  const int wid = tid >> 6, lane = tid & 63;
  const int q = (wid < 7) ? wid * 8 : (wid - 7) * 8 + 1;

  int ap[4];
#pragma unroll
  for (int p = 0; p < 4; ++p) ap[p] = ((b * 56 + h) * 56 + q + 2 * p) * 49;

  float acc[4][4] = {};
  const f16* rowb = xpad + ((size_t)(b * 68 + h) * 68 + q) * 256 + 4 * lane;

  for (int i = 0; i < 7; ++i) {
    const f16* rb = rowb + (size_t)(2 * i * 68) * 256;
#pragma unroll
    for (int tt = 0; tt < 10; ++tt) {
      f16x4 xv = *(const f16x4*)(rb + tt * 512);  // 2 cols per tt step
      float xf[4];
#pragma unroll
      for (int k = 0; k < 4; ++k) xf[k] = (float)xv[k];
#pragma unroll
      for (int p = 0; p < 4; ++p) {
        const int j = tt - p;
        if (j >= 0 && j < 7) {
          const float a = attn[ap[p] + i * 7 + j];
#pragma unroll
          for (int k = 0; k < 4; ++k) acc[p][k] = fmaf(a, xf[k], acc[p][k]);
        }
      }
    }
  }

#pragma unroll
  for (int p = 0; p < 4; ++p)
#pragma unroll
    for (int k = 0; k < 4; ++k) t[4 * lane + k][q + 2 * p] = acc[p][k];
  __syncthreads();
  float* ob = out + ((size_t)b * 256 * 56 + h) * 56;
  for (int f = tid; f < 256 * 56; f += 896) {
    int c = f / 56, w = f % 56;
    ob[(size_t)c * 3136 + w] = t[c][w];
  }
}

// ---------------- launch ----------------
extern "C" void kernel_launch(void* const* d_in, const int* in_sizes, int n_in,
                              void* d_out, int out_size, void* d_ws,
                              size_t ws_size, hipStream_t stream) {
  const float* x = (const float*)d_in[0];
  const float* w1 = (const float*)d_in[1];
  const float* b1 = (const float*)d_in[2];
  const float* w2 = (const float*)d_in[3];
  const float* b2 = (const float*)d_in[4];
  const float* gamma = (const float*)d_in[5];
  const float* beta = (const float*)d_in[6];
  const float* rmean = (const float*)d_in[7];
  const float* rvar = (const float*)d_in[8];
  float* out = (float*)d_out;

  char* ws = (char*)d_ws;
  f16* xpad = (f16*)ws;                     // 16*68*68*256*2 = 37,879,808 B
  f16* w1h = (f16*)(ws + 37879808);         // 49*128*256*2  =  3,211,264 B
  f16* kbuf = (f16*)(ws + 41091072);        // 2*50176*128*2 = 25,690,112 B
  float* attn = (float*)(ws + 66781184);    // 50176*49*4    =  9,834,496 B

  hipLaunchKernelGGL(prep_misc, dim3(3104), dim3(256), 0, stream, w1, w1h,
                     (uint4*)xpad);
  hipLaunchKernelGGL(transpose_cast, dim3(896), dim3(256), 0, stream, x, xpad);
  hipLaunchKernelGGL(conv1_gemm, dim3(448), dim3(256), 0, stream, xpad, w1h,
                     kbuf);
  hipLaunchKernelGGL(conv2_bn_softmax, dim3(784), dim3(64), 0, stream, kbuf,
                     b1, w2, b2, gamma, beta, rmean, rvar, attn);
  hipLaunchKernelGGL(aggregate2, dim3(896), dim3(896), 0, stream, xpad, attn,
                     out);
}

// Round 17
// 243.881 us; speedup vs baseline: 1.2080x; 1.0022x over previous
//
#include <hip/hip_runtime.h>

typedef _Float16 f16;
typedef __attribute__((__ext_vector_type__(2))) _Float16 f16x2;
typedef __attribute__((__ext_vector_type__(4))) _Float16 f16x4;
typedef __attribute__((__ext_vector_type__(8))) _Float16 f16x8;
typedef __attribute__((__ext_vector_type__(4))) float f32x4;

#define GLDS16(g, l) __builtin_amdgcn_global_load_lds( \
    (const __attribute__((address_space(1))) void*)(g), \
    (__attribute__((address_space(3))) void*)(l), 16, 0, 0)

// ---------------- constants ----------------
// x: (16,256,56,56)  w1: (128,256,7,7) dil=2 pad=6 -> k:(16,128,56,56)
// w2: (49,128) -> attn (16,49,56,56); out = sum_ij tap(x) * attn
// padded spatial 68x68 (orig (h,w) at padded (h+6,w+6); tap (i,j) of output
// (h,w) reads padded array index (h+2i, w+2j)).

// ---- fully fused prep: w1 layout | zero border | transpose+cast --------
// Order matters for L2 state at conv1 start: w1t first (blocks 0..127),
// border zeros middle (128..3103), transpose LAST (3104..3999) so the
// xpad interior is freshest in L2 (r7's regression had border last).
__global__ __launch_bounds__(256) void prep_all(
    const float* __restrict__ x, const float* __restrict__ w1,
    f16* __restrict__ w1h, f16* __restrict__ xpad) {
  const int blk = blockIdx.x;
  const int tid = threadIdx.x;
  if (blk < 128) {
    // w1 (co,c,i,j) fp32 -> per-wave-fragment lane order (thread/(co,c)):
    // elem = (((ij*8 + half*4 + cc)*8 + f)*64 + q*16 + l15)*8 + e
    //   co = f*16 + l15;  c = half*128 + cc*32 + q*8 + e
    const int idx = blk * 256 + tid;  // 0..32767
    const int co = idx >> 8, c = idx & 255;
    const int half = c >> 7, cc = (c >> 5) & 3, q = (c >> 3) & 3, e = c & 7;
    const int f = co >> 4, l15 = co & 15;
    const size_t base =
        ((((size_t)(half * 4 + cc) * 8 + f) * 64 + q * 16 + l15) * 8 + e);
    const float* src = w1 + ((size_t)co * 256 + c) * 49;
#pragma unroll 7
    for (int ij = 0; ij < 49; ++ij)
      w1h[base + (size_t)ij * 32768] = (f16)src[ij];
  } else if (blk < 3104) {
    // zero the 12.2MB xpad border (interior overwritten by transpose)
    const int i = (blk - 128) * 256 + tid;  // 0..761855
    uint4* xp4 = (uint4*)xpad;
    int idx4;
    if (i < 417792) {  // full rows: 16b x 12r x 2176 u4
      int u = i % 2176;
      int row12 = i / 2176;
      int b = row12 / 12, r12 = row12 % 12;
      int r = (r12 < 6) ? r12 : r12 + 56;
      idx4 = (b * 68 + r) * 2176 + u;
    } else {  // side runs: 16b x 56r x 2 sides x 192 u4
      int j = i - 417792;
      int u = j % 192;
      int run = j / 192;
      int side = run & 1;
      int br = run >> 1;
      int r = br % 56 + 6, b = br / 56;
      idx4 = (b * 68 + r) * 2176 + (side ? 62 * 32 : 0) + u;
    }
    xp4[idx4] = make_uint4(0u, 0u, 0u, 0u);
  } else {
    // x NCHW fp32 -> xpad NHWC fp16 interior row (b,h); float4 reads.
    __shared__ f16 t16[56][258];
    const int bh = blk - 3104;
    const int h = bh % 56, b = bh / 56;
    const float4* xp4 =
        (const float4*)(x + (size_t)b * 256 * 3136 + (size_t)h * 56);
    for (int f = tid; f < 256 * 14; f += 256) {
      int c = f / 14, w4 = f % 14;
      float4 v = xp4[(size_t)c * 784 + w4];  // row stride 3136 f32 = 784 f4
      int w = w4 * 4;
      t16[w + 0][c] = (f16)v.x;
      t16[w + 1][c] = (f16)v.y;
      t16[w + 2][c] = (f16)v.z;
      t16[w + 3][c] = (f16)v.w;
    }
    __syncthreads();
    f16* op = xpad + (((size_t)(b * 68) + h + 6) * 68 + 6) * 256;
    for (int g = tid; g < 56 * 32; g += 256) {
      int w = g >> 5, c0 = (g & 31) * 8;
      *(f16x8*)(op + (size_t)w * 256 + c0) = *(const f16x8*)&t16[w][c0];
    }
  }
}

// ---------------- conv1: 4-row-strip implicit GEMM, A double-buffer -----
// FROZEN r13/r15 form (best measured: 141us, MfmaUtil 51%). Block = (b,
// 4-row strip, channel-half), 2 blocks/CU (>=2 waves/SIMD hard constraint
// -- r14's 1-block/CU merged-K regressed to 204us). A: XOR-swizzled strip
// staged per cc slice; tap-level A register double-buffer hides the LDS
// pipe under MFMA. B: 1-tap-ahead register prefetch from w1h (L2-hot).
__global__ __launch_bounds__(256, 2) void conv1_gemm(
    const f16* __restrict__ xpad, const f16* __restrict__ w1h,
    f16* __restrict__ kbuf) {
  __shared__ f16 strip[16 * 68 * 32];  // 69632 B

  const int tid = threadIdx.x;
  const int wid = tid >> 6, lane = tid & 63;
  // XCD-chunked bijective swizzle (448 % 8 == 0)
  const int pphys = blockIdx.x;
  const int bid = (pphys & 7) * 56 + (pphys >> 3);
  const int half = bid & 1;
  const int sid = bid >> 1;  // 0..223
  const int b = sid / 14;
  const int h0 = (sid % 14) * 4;

  const int l15 = lane & 15;
  const int q = lane >> 4;        // ch-quarter (16B) index
  const int qb = (l15 >> 1) & 3;  // (w>>1)&3, m-independent

  const int mbase = (wid >> 1) * 7;
  const int nbase = (wid & 1) * 4;

  int arow_off[7];
#pragma unroll
  for (int mm = 0; mm < 7; ++mm) {
    int p = (mbase + mm) * 16 + l15;
    int rw = p / 56;
    int w = p - 56 * rw;
    arow_off[mm] = (rw * 68 + w) * 64;
  }

  const char* xg = (const char*)xpad +
                   ((size_t)(b * 68 + h0)) * (68 * 512) + half * 256;
  const char* wB = (const char*)w1h;
  char* Ss = (char*)strip;

  const int half4 = half * 4;
  auto loadB = [&](int cc, int ij, int nn) -> f16x8 {
    int off = (((ij * 8 + half4 + cc) * 8 + nbase + nn) * 64 + lane) * 16;
    return *(const f16x8*)(wB + off);
  };
  auto baseOff = [&](int ij) -> int {
    const int i = (int)((unsigned)ij / 7u);
    const int j = ij - 7 * i;
    return i * 8704 + j * 128 + ((q ^ ((qb + j) & 3)) << 4);
  };

  f32x4 acc[7][4] = {};
  f16x8 pb0 = loadB(0, 0, 0), pb1 = loadB(0, 0, 1);
  f16x8 pb2 = loadB(0, 0, 2), pb3 = loadB(0, 0, 3);
  f16x8 A0[7], A1[7];

  for (int cc = 0; cc < 4; ++cc) {
    const int chb = cc * 64;
    __syncthreads();  // prior cc's consumers done with strip
#pragma unroll
    for (int rr = 0; rr < 17; ++rr) {
      int s = rr * 256 + tid;  // 16B-slot: s = r*272 + col*4 + q4
      int r = (int)((unsigned)s / 272u);
      int rem = s - r * 272;
      int col = rem >> 2, q4 = rem & 3;
      int qq = q4 ^ ((col >> 1) & 3);  // pre-swizzled source quarter
      GLDS16(xg + (size_t)r * (68 * 512) + col * 512 + chb + qq * 16,
             Ss + (rr * 256 + wid * 64) * 16);
    }
    __syncthreads();  // strip ready

    // prologue: A0 <- tap 0 of this cc
    {
      const int bo = baseOff(0);
#pragma unroll
      for (int mm = 0; mm < 7; ++mm)
        A0[mm] = *(const f16x8*)(Ss + arow_off[mm] + bo);
    }

    auto tapStep = [&](f16x8* Acur, f16x8* Anxt, int ij, bool loadA) {
      f16x8 b0 = pb0, b1 = pb1, b2 = pb2, b3 = pb3;
      int nij = ij + 1, ncc = cc;
      if (nij == 49) { nij = 0; ++ncc; }
      if (ncc < 4) {
        pb0 = loadB(ncc, nij, 0);
        pb1 = loadB(ncc, nij, 1);
        pb2 = loadB(ncc, nij, 2);
        pb3 = loadB(ncc, nij, 3);
      }
      if (loadA) {
        const int bo = baseOff(ij + 1);
#pragma unroll
        for (int mm = 0; mm < 7; ++mm)
          Anxt[mm] = *(const f16x8*)(Ss + arow_off[mm] + bo);
      }
#pragma unroll
      for (int mm = 0; mm < 7; ++mm) {
        acc[mm][0] = __builtin_amdgcn_mfma_f32_16x16x32_f16(Acur[mm], b0,
                                                            acc[mm][0], 0, 0, 0);
        acc[mm][1] = __builtin_amdgcn_mfma_f32_16x16x32_f16(Acur[mm], b1,
                                                            acc[mm][1], 0, 0, 0);
        acc[mm][2] = __builtin_amdgcn_mfma_f32_16x16x32_f16(Acur[mm], b2,
                                                            acc[mm][2], 0, 0, 0);
        acc[mm][3] = __builtin_amdgcn_mfma_f32_16x16x32_f16(Acur[mm], b3,
                                                            acc[mm][3], 0, 0, 0);
      }
    };

    for (int pt = 0; pt < 24; ++pt) {
      tapStep(A0, A1, 2 * pt, true);      // consume A0, fill A1
      tapStep(A1, A0, 2 * pt + 1, true);  // consume A1, fill A0
    }
    tapStep(A0, A1, 48, false);  // tail tap, no A prefetch
  }

  // write fp16 partials: kh[p][co], p = (b*56 + h0 + rw)*56 + w
  f16* kh = kbuf + (size_t)half * (50176 * 128);
  const int pbase = (b * 56 + h0) * 56;
#pragma unroll
  for (int mm = 0; mm < 7; ++mm) {
#pragma unroll
    for (int nn = 0; nn < 4; ++nn) {
      const int co = (nbase + nn) * 16 + l15;
#pragma unroll
      for (int r = 0; r < 4; ++r) {
        int p = (mbase + mm) * 16 + q * 4 + r;
        int rw = p / 56;
        int w = p - 56 * rw;
        kh[(size_t)(pbase + rw * 56 + w) * 128 + co] = (f16)acc[mm][nn][r];
      }
    }
  }
}

// ---------------- sum halves + bias + relu + 1x1 + BN + softmax ---------
__global__ __launch_bounds__(64) void conv2_bn_softmax(
    const f16* __restrict__ kbuf, const float* __restrict__ b1,
    const float* __restrict__ w2, const float* __restrict__ b2,
    const float* __restrict__ gamma, const float* __restrict__ beta,
    const float* __restrict__ rmean, const float* __restrict__ rvar,
    float* __restrict__ attn) {
  __shared__ f16 w2s[49 * 128];
  __shared__ float b1s[128];
  __shared__ float outs[64 * 49];
  for (int i = threadIdx.x; i < 49 * 128; i += 64) w2s[i] = (f16)w2[i];
  for (int i = threadIdx.x; i < 128; i += 64) b1s[i] = b1[i];
  __syncthreads();
  const int p = blockIdx.x * 64 + threadIdx.x;
  float acc[49];
#pragma unroll
  for (int o = 0; o < 49; ++o) acc[o] = 0.f;
  const f16x8* ka = (const f16x8*)(kbuf + (size_t)p * 128);
  const f16x8* kb = (const f16x8*)(kbuf + (size_t)50176 * 128 + (size_t)p * 128);
  for (int u = 0; u < 16; ++u) {
    f16x8 va = ka[u], vb = kb[u];
    f16x2 kvh[4];
#pragma unroll
    for (int j = 0; j < 4; ++j) {
      float s0 = (float)va[2 * j] + (float)vb[2 * j] + b1s[u * 8 + 2 * j];
      float s1 =
          (float)va[2 * j + 1] + (float)vb[2 * j + 1] + b1s[u * 8 + 2 * j + 1];
      s0 = s0 > 0.f ? s0 : 0.f;
      s1 = s1 > 0.f ? s1 : 0.f;
      kvh[j] = f16x2{(f16)s0, (f16)s1};
    }
#pragma unroll
    for (int o = 0; o < 49; ++o) {
      f16x8 wv = *(const f16x8*)(w2s + o * 128 + u * 8);
#if __has_builtin(__builtin_amdgcn_fdot2)
      acc[o] = __builtin_amdgcn_fdot2(kvh[0], f16x2{wv[0], wv[1]}, acc[o], false);
      acc[o] = __builtin_amdgcn_fdot2(kvh[1], f16x2{wv[2], wv[3]}, acc[o], false);
      acc[o] = __builtin_amdgcn_fdot2(kvh[2], f16x2{wv[4], wv[5]}, acc[o], false);
      acc[o] = __builtin_amdgcn_fdot2(kvh[3], f16x2{wv[6], wv[7]}, acc[o], false);
#else
#pragma unroll
      for (int j = 0; j < 4; ++j)
        acc[o] += (float)kvh[j][0] * (float)wv[2 * j] +
                  (float)kvh[j][1] * (float)wv[2 * j + 1];
#endif
    }
  }
  float mx = -1e30f;
#pragma unroll
  for (int o = 0; o < 49; ++o) {
    float s = acc[o] + b2[o];
    float inv = gamma[o] * rsqrtf(rvar[o] + 1e-5f);
    s = (s - rmean[o]) * inv + beta[o];
    s = s > 0.f ? s : 0.f;
    acc[o] = s;
    mx = fmaxf(mx, s);
  }
  float sum = 0.f;
#pragma unroll
  for (int o = 0; o < 49; ++o) {
    float e = __expf(acc[o] - mx);
    acc[o] = e;
    sum += e;
  }
  const float rinv = 1.f / sum;
  float* orow = outs + threadIdx.x * 49;
#pragma unroll
  for (int o = 0; o < 49; ++o) orow[o] = acc[o] * rinv;
  __syncthreads();
  float* ab = attn + (size_t)blockIdx.x * (64 * 49);
  for (int i = threadIdx.x; i < 64 * 49; i += 64) ab[i] = outs[i];
}

// ---------------- attention-weighted aggregation (r8 scalar form) -------
__global__ __launch_bounds__(896, 1) void aggregate2(
    const f16* __restrict__ xpad, const float* __restrict__ attn,
    float* __restrict__ out) {
  __shared__ float t[256][57];  // 58368 B
  const int pp = blockIdx.x;
  const int bh = (pp & 7) * 112 + (pp >> 3);  // bijective: 896 = 8*112
  const int h = bh % 56, b = bh / 56;
  const int tid = threadIdx.x;
  const int wid = tid >> 6, lane = tid & 63;
  const int q = (wid < 7) ? wid * 8 : (wid - 7) * 8 + 1;

  int ap[4];
#pragma unroll
  for (int p = 0; p < 4; ++p) ap[p] = ((b * 56 + h) * 56 + q + 2 * p) * 49;

  float acc[4][4] = {};
  const f16* rowb = xpad + ((size_t)(b * 68 + h) * 68 + q) * 256 + 4 * lane;

  for (int i = 0; i < 7; ++i) {
    const f16* rb = rowb + (size_t)(2 * i * 68) * 256;
#pragma unroll
    for (int tt = 0; tt < 10; ++tt) {
      f16x4 xv = *(const f16x4*)(rb + tt * 512);  // 2 cols per tt step
      float xf[4];
#pragma unroll
      for (int k = 0; k < 4; ++k) xf[k] = (float)xv[k];
#pragma unroll
      for (int p = 0; p < 4; ++p) {
        const int j = tt - p;
        if (j >= 0 && j < 7) {
          const float a = attn[ap[p] + i * 7 + j];
#pragma unroll
          for (int k = 0; k < 4; ++k) acc[p][k] = fmaf(a, xf[k], acc[p][k]);
        }
      }
    }
  }

#pragma unroll
  for (int p = 0; p < 4; ++p)
#pragma unroll
    for (int k = 0; k < 4; ++k) t[4 * lane + k][q + 2 * p] = acc[p][k];
  __syncthreads();
  float* ob = out + ((size_t)b * 256 * 56 + h) * 56;
  for (int f = tid; f < 256 * 56; f += 896) {
    int c = f / 56, w = f % 56;
    ob[(size_t)c * 3136 + w] = t[c][w];
  }
}

// ---------------- launch ----------------
extern "C" void kernel_launch(void* const* d_in, const int* in_sizes, int n_in,
                              void* d_out, int out_size, void* d_ws,
                              size_t ws_size, hipStream_t stream) {
  const float* x = (const float*)d_in[0];
  const float* w1 = (const float*)d_in[1];
  const float* b1 = (const float*)d_in[2];
  const float* w2 = (const float*)d_in[3];
  const float* b2 = (const float*)d_in[4];
  const float* gamma = (const float*)d_in[5];
  const float* beta = (const float*)d_in[6];
  const float* rmean = (const float*)d_in[7];
  const float* rvar = (const float*)d_in[8];
  float* out = (float*)d_out;

  char* ws = (char*)d_ws;
  f16* xpad = (f16*)ws;                     // 16*68*68*256*2 = 37,879,808 B
  f16* w1h = (f16*)(ws + 37879808);         // 49*128*256*2  =  3,211,264 B
  f16* kbuf = (f16*)(ws + 41091072);        // 2*50176*128*2 = 25,690,112 B
  float* attn = (float*)(ws + 66781184);    // 50176*49*4    =  9,834,496 B

  hipLaunchKernelGGL(prep_all, dim3(4000), dim3(256), 0, stream, x, w1, w1h,
                     xpad);
  hipLaunchKernelGGL(conv1_gemm, dim3(448), dim3(256), 0, stream, xpad, w1h,
                     kbuf);
  hipLaunchKernelGGL(conv2_bn_softmax, dim3(784), dim3(64), 0, stream, kbuf,
                     b1, w2, b2, gamma, beta, rmean, rvar, attn);
  hipLaunchKernelGGL(aggregate2, dim3(896), dim3(896), 0, stream, xpad, attn,
                     out);
}